// Round 19
// baseline (75.228 us; speedup 1.0000x reference)
//
#include <hip/hip_runtime.h>

typedef __attribute__((ext_vector_type(4))) float f32x4;
typedef __attribute__((ext_vector_type(16))) float f32x16;
typedef __attribute__((ext_vector_type(8))) _Float16 f16x8;

#define D_ 64
#define K_ 512

// SCREEN + REFINE on mfma_f32_32x32x16_f16.
// Screen score = 0.5||e||^2 (fp32, C seed) + Sum eh_d * (-c)h_d  (hi limbs only,
// 8 MFMA/qt). Missing terms bounded by B(q) = CH*cln(q) + CL*chn(q) + CL*cln(q)
// + 2e-3 (CH/CL = block-max entry hi/lo limb norms; chn/cln = query limb norms).
// Queries with global top-2 margin <= B(q) are re-argmin'd EXACTLY (double) by
// one wave over all 512 entries (expected ~0.2-2% of queries).
// Operand slot (lane>>5, s) = dim-pos within k-block, IDENTICAL builder both
// sides => permutation cancels (validated r15-r18, absmax 0.0).
// C/D (HW m74/m101): col = lane&31 = query, row = (reg&3)+8*(reg>>2)+4*(lane>>5).
__global__ __launch_bounds__(512, 2)
void vq_fused(const float* __restrict__ codes,
              const float* __restrict__ codebook,
              float* __restrict__ out) {
  __shared__ _Float16 Af[256 * 64];      // 32 KB: qtile*2048 + kb*512 + ph*256 + qr*8
  __shared__ float esq_s[K_];            // 2 KB
  __shared__ float qchn2[256], qcln2[256];
  __shared__ float wmaxh[8], wmaxl[8];
  __shared__ float smin[8][256];         // 8 KB (screen best)
  __shared__ float smin2[8][256];        // 8 KB (screen second)
  __shared__ int   simin[8][256];        // 8 KB
  __shared__ int   best[256];
  __shared__ int   list_s[256];
  __shared__ int   nref;

  const int t = threadIdx.x;
  const int w = t >> 6, l = t & 63;
  const int l32 = l & 31, lhi = l >> 5;
  const long long qb = (long long)blockIdx.x * 256;

  if (t == 0) nref = 0;

  // ---- issue query loads first ----
  const int ql = t >> 1, dhalf = (t & 1) * 32;
  const float* asrc = codes + (qb + ql) * D_ + dhalf;
  f32x4 av[8];
#pragma unroll
  for (int g = 0; g < 8; ++g) av[g] = *(const f32x4*)(asrc + 4 * g);

  // ---- build ef HI frags + 0.5||e||^2 + limb norms (entries 64w..64w+63) ----
  f16x8 ef[2][4];
  float maxh2 = 0.f, maxl2 = 0.f;
#pragma unroll
  for (int i = 0; i < 2; ++i) {
    const int e = w * 64 + i * 32 + l32;
    float es = 0.f, ehn2 = 0.f, eln2 = 0.f;
#pragma unroll
    for (int kb = 0; kb < 4; ++kb) {
      const float* src = codebook + e * D_ + kb * 16 + lhi * 8;
      f32x4 v0 = *(const f32x4*)src;
      f32x4 v1 = *(const f32x4*)(src + 4);
#pragma unroll
      for (int s = 0; s < 8; ++s) {
        float a = (s < 4) ? v0[s & 3] : v1[s & 3];
        es += a * a;
        _Float16 h = (_Float16)a;
        float hf = (float)h, lo = a - hf;
        ehn2 += hf * hf;
        eln2 += lo * lo;
        ef[i][kb][s] = h;
      }
    }
    es += __shfl_xor(es, 32, 64);        // lane pair covers all 64 dims
    ehn2 += __shfl_xor(ehn2, 32, 64);
    eln2 += __shfl_xor(eln2, 32, 64);
    if (lhi == 0) esq_s[e] = 0.5f * es;
    maxh2 = fmaxf(maxh2, ehn2);
    maxl2 = fmaxf(maxl2, eln2);
  }
#pragma unroll
  for (int off = 1; off < 64; off <<= 1) {
    maxh2 = fmaxf(maxh2, __shfl_xor(maxh2, off, 64));
    maxl2 = fmaxf(maxl2, __shfl_xor(maxl2, off, 64));
  }
  if (l == 0) { wmaxh[w] = maxh2; wmaxl[w] = maxl2; }

  // ---- stage query HI frags (negated) + query limb norms ----
  {
    float chn2 = 0.f, cln2 = 0.f;
    const int kb0 = (t & 1) * 2;
    const int qtile = ql >> 5, qr = ql & 31;
#pragma unroll
    for (int kk = 0; kk < 2; ++kk)
#pragma unroll
      for (int ph = 0; ph < 2; ++ph) {
        f16x8 wh;
#pragma unroll
        for (int s = 0; s < 8; ++s) {
          float na = -av[kk * 4 + ph * 2 + (s >> 2)][s & 3];
          _Float16 h = (_Float16)na;
          float hf = (float)h, lo = na - hf;
          chn2 += hf * hf;
          cln2 += lo * lo;
          wh[s] = h;
        }
        *(f16x8*)(Af + qtile * 2048 + (kb0 + kk) * 512 + ph * 256 + qr * 8) = wh;
      }
    chn2 += __shfl_xor(chn2, 1, 64);     // combine the two dim-halves
    cln2 += __shfl_xor(cln2, 1, 64);
    if ((t & 1) == 0) { qchn2[ql] = chn2; qcln2[ql] = cln2; }
  }
  __syncthreads();                       // barrier #1

  f32x4 esqr[2][4];
#pragma unroll
  for (int i = 0; i < 2; ++i)
#pragma unroll
    for (int g = 0; g < 4; ++g)
      esqr[i][g] = *(const f32x4*)(esq_s + w * 64 + i * 32 + 8 * g + 4 * lhi);

  const _Float16* qbase = Af + lhi * 256 + l32 * 8;

  // top-2 fold + cross-half merge + smin write
  auto finish = [&](const f32x16& a0, const f32x16& a1, int qt) {
    float m1 = 3.4e38f, m2 = 3.4e38f; int i1 = 0;
#pragma unroll
    for (int g = 0; g < 4; ++g)
#pragma unroll
      for (int r = 0; r < 4; ++r) {
        const float v = a0[4 * g + r];
        const int e0 = w * 64 + 8 * g + 4 * lhi + r;
        if (v < m1) { m2 = m1; m1 = v; i1 = e0; } else if (v < m2) m2 = v;
      }
#pragma unroll
    for (int g = 0; g < 4; ++g)
#pragma unroll
      for (int r = 0; r < 4; ++r) {
        const float v = a1[4 * g + r];
        const int e1 = w * 64 + 32 + 8 * g + 4 * lhi + r;
        if (v < m1) { m2 = m1; m1 = v; i1 = e1; } else if (v < m2) m2 = v;
      }
    float om1 = __shfl_xor(m1, 32, 64);
    int oi1 = __shfl_xor(i1, 32, 64);
    float om2 = __shfl_xor(m2, 32, 64);
    if (om1 < m1 || (om1 == m1 && oi1 < i1)) {
      m2 = fminf(m1, om2); m1 = om1; i1 = oi1;
    } else {
      m2 = fminf(m2, om1);
    }
    if (lhi == 0) {
      smin[w][qt * 32 + l32] = m1;
      smin2[w][qt * 32 + l32] = m2;
      simin[w][qt * 32 + l32] = i1;
    }
  };

  auto mfma8 = [&](const f16x8* qf, f32x16& a0, f32x16& a1) {
#pragma unroll
    for (int g = 0; g < 4; ++g)
#pragma unroll
      for (int r = 0; r < 4; ++r) {
        a0[4 * g + r] = esqr[0][g][r];
        a1[4 * g + r] = esqr[1][g][r];
      }
    __builtin_amdgcn_s_setprio(1);
#pragma unroll
    for (int kb = 0; kb < 4; ++kb) {     // eh . (-ch)
      a0 = __builtin_amdgcn_mfma_f32_32x32x16_f16(ef[0][kb], qf[kb], a0, 0, 0, 0);
      a1 = __builtin_amdgcn_mfma_f32_32x32x16_f16(ef[1][kb], qf[kb], a1, 0, 0, 0);
    }
    __builtin_amdgcn_s_setprio(0);
  };

  // ---- screen loop: 8 q-tiles, software-pipelined qf double-buffer ----
  f16x8 qfA[4], qfB[4];
#pragma unroll
  for (int kb = 0; kb < 4; ++kb)
    qfA[kb] = *(const f16x8*)(qbase + 0 * 2048 + kb * 512);

#pragma unroll
  for (int qt = 0; qt < 8; qt += 2) {
#pragma unroll
    for (int kb = 0; kb < 4; ++kb)       // prefetch qt+1 before qt's burst
      qfB[kb] = *(const f16x8*)(qbase + (qt + 1) * 2048 + kb * 512);

    f32x16 a0, a1;
    mfma8(qfA, a0, a1);

    if (qt + 2 < 8) {
#pragma unroll
      for (int kb = 0; kb < 4; ++kb)
        qfA[kb] = *(const f16x8*)(qbase + (qt + 2) * 2048 + kb * 512);
    }
    finish(a0, a1, qt);

    f32x16 b0, b1;
    mfma8(qfB, b0, b1);
    finish(b0, b1, qt + 1);
  }
  __syncthreads();                       // barrier #2

  // ---- combine 8 waves + ambiguity test ----
  if (t < 256) {
    float b1 = smin[0][t], b2 = smin2[0][t];
    int i1 = simin[0][t];
#pragma unroll
    for (int ww = 1; ww < 8; ++ww) {
      float v = smin[ww][t], v2 = smin2[ww][t];
      int ii = simin[ww][t];
      if (v < b1 || (v == b1 && ii < i1)) {
        b2 = fminf(b1, v2); b1 = v; i1 = ii;
      } else {
        b2 = fminf(b2, v);
      }
    }
    float CH2 = 0.f, CL2 = 0.f;
#pragma unroll
    for (int ww = 0; ww < 8; ++ww) {
      CH2 = fmaxf(CH2, wmaxh[ww]);
      CL2 = fmaxf(CL2, wmaxl[ww]);
    }
    const float CH = sqrtf(CH2), CL = sqrtf(CL2);
    const float chn = sqrtf(qchn2[t]), cln = sqrtf(qcln2[t]);
    const float B = CH * cln + CL * chn + CL * cln + 2e-3f;
    best[t] = i1;
    if (b2 - b1 <= B) {
      int k = atomicAdd(&nref, 1);
      list_s[k] = t;
    }
  }
  __syncthreads();                       // barrier #3

  // ---- exact refine (double) for flagged queries: one wave per query ----
  {
    const int nr = nref;
    for (int k = w; k < nr; k += 8) {
      const int q = list_s[k];
      const float* crow = codes + (qb + q) * D_;
      double bs = 1e300; int bi = 0;
      for (int j = 0; j < 8; ++j) {
        const int e = l + 64 * j;        // ascending within lane
        const float* erow = codebook + e * D_;
        double s = 0.0;
#pragma unroll 8
        for (int d = 0; d < 64; ++d) {
          double ed = (double)erow[d];
          s += ed * (0.5 * ed - (double)crow[d]);
        }
        if (s < bs) { bs = s; bi = e; }
      }
#pragma unroll
      for (int off = 1; off < 64; off <<= 1) {
        double ov = __shfl_xor(bs, off, 64);
        int oi = __shfl_xor(bi, off, 64);
        if (ov < bs || (ov == bs && oi < bi)) { bs = ov; bi = oi; }
      }
      if (l == 0) best[q] = bi;
    }
  }
  __syncthreads();                       // barrier #4

  // ---- gather: exact fp32 rows (L2-hot codebook), coalesced NT stores ----
#pragma unroll
  for (int i2 = 0; i2 < 8; ++i2) {
    const int f = t + 512 * i2;          // 4096 f32x4 per block
    const int q = f >> 4, g = f & 15;
    const int e = best[q];
    f32x4 v = *(const f32x4*)(codebook + e * D_ + g * 4);
    __builtin_nontemporal_store(v, (f32x4*)(out + (qb + q) * D_ + g * 4));
  }
}

extern "C" void kernel_launch(void* const* d_in, const int* in_sizes, int n_in,
                              void* d_out, int out_size, void* d_ws, size_t ws_size,
                              hipStream_t stream) {
  const float* codes = (const float*)d_in[0];
  const float* codebook = (const float*)d_in[1];
  float* out = (float*)d_out;
  const int Q = in_sizes[0] / D_;        // 65536
  const int grid = Q / 256;              // 256
  vq_fused<<<grid, 512, 0, stream>>>(codes, codebook, out);
}

// Round 20
// 24.447 us; speedup vs baseline: 3.0772x; 3.0772x over previous
//
#include <hip/hip_runtime.h>

typedef __attribute__((ext_vector_type(4))) float f32x4;
typedef __attribute__((ext_vector_type(16))) float f32x16;
typedef __attribute__((ext_vector_type(8))) _Float16 f16x8;

#define D_ 64
#define K_ 512

// 2-limb f16 (a = hi + lo, 22 mantissa bits) on mfma_f32_32x32x16_f16.
// K-space = 128 limbs in 8 k-blocks of 16: kb 0-3 = hi(dims 16kb..16kb+15),
// kb 4-7 = lo. Operand slot (lane>>5, s) holds dim-pos (lane>>5)*8 + s —
// IDENTICAL builder for entries (A) and queries (B) => within-k-block
// permutation cancels in A.B (validated r15-r18: absmax 0.0).
// Queries NEGATED; acc seeded with 0.5||e||^2: score = 0.5||e||^2 - c.e
// (lo.lo dropped, ~1.5e-5; r19 proved the hi.lo terms CANNOT also be dropped:
// their bound ~0.08 matches the typical top-2 gap -> mass refine).
// C/D (HW m74/m101): col = lane&31 = query, row = (reg&3)+8*(reg>>2)+4*(lane>>5).
//
// SESSION-BEST STRUCTURE (r18 = r15 + software-pipelined qf double-buffer +
// s_setprio around MFMA clusters; barrier-free drifting waves).
__global__ __launch_bounds__(512, 2)
void vq_fused(const float* __restrict__ codes,
              const float* __restrict__ codebook,
              float* __restrict__ out) {
  __shared__ _Float16 Af[256 * 128];     // 64 KB query frags
  __shared__ float esq_s[K_];            // 2 KB
  __shared__ float smin[8][256];         // 8 KB
  __shared__ int   simin[8][256];        // 8 KB
  __shared__ int   best[256];            // 1 KB

  const int t = threadIdx.x;
  const int w = t >> 6, l = t & 63;
  const int l32 = l & 31, lhi = l >> 5;
  const long long qb = (long long)blockIdx.x * 256;

  // ---- issue query loads first: thread -> query ql, dims dhalf..dhalf+31 ----
  const int ql = t >> 1, dhalf = (t & 1) * 32;
  const float* asrc = codes + (qb + ql) * D_ + dhalf;
  f32x4 av[8];
#pragma unroll
  for (int g = 0; g < 8; ++g) av[g] = *(const f32x4*)(asrc + 4 * g);

  // ---- build ef frags + 0.5||e||^2 (wave owns entries 64w..64w+63) ----
  f16x8 ef[2][8];                        // [tile][kb] kb0-3 hi, kb4-7 lo
#pragma unroll
  for (int i = 0; i < 2; ++i) {
    const int e = w * 64 + i * 32 + l32;
    float es = 0.f;
#pragma unroll
    for (int kb = 0; kb < 4; ++kb) {
      const float* src = codebook + e * D_ + kb * 16 + lhi * 8;
      f32x4 v0 = *(const f32x4*)src;
      f32x4 v1 = *(const f32x4*)(src + 4);
#pragma unroll
      for (int s = 0; s < 8; ++s) {
        float a = (s < 4) ? v0[s & 3] : v1[s & 3];
        es += a * a;
        _Float16 h = (_Float16)a;
        ef[i][kb][s] = h;
        ef[i][4 + kb][s] = (_Float16)(a - (float)h);
      }
    }
    es += __shfl_xor(es, 32, 64);        // lane pair covers all 64 dims
    if (lhi == 0) esq_s[e] = 0.5f * es;
  }

  // ---- stage queries: negated 2-limb frags, 8 x ds_write_b128 ----
  {
    const int kbs = (t & 1) * 2;         // thread's two k-blocks
    const int qtile = ql >> 5, qr = ql & 31;
#pragma unroll
    for (int kk = 0; kk < 2; ++kk)
#pragma unroll
      for (int ph = 0; ph < 2; ++ph) {
        f16x8 wh, wl;
#pragma unroll
        for (int s = 0; s < 8; ++s) {
          float na = -av[kk * 4 + ph * 2 + (s >> 2)][s & 3];
          _Float16 h = (_Float16)na;
          wh[s] = h;
          wl[s] = (_Float16)(na - (float)h);
        }
        _Float16* dst = Af + qtile * 4096 + (kbs + kk) * 512 + ph * 256 + qr * 8;
        *(f16x8*)dst = wh;               // hi k-block
        *(f16x8*)(dst + 2048) = wl;      // lo k-block (kb+4)
      }
  }
  __syncthreads();                       // barrier #1: Af + esq_s ready

  // per-lane 0.5||e||^2 for C/D rows: row(reg) = (reg&3) + 8*(reg>>2) + 4*lhi
  f32x4 esqr[2][4];
#pragma unroll
  for (int i = 0; i < 2; ++i)
#pragma unroll
    for (int g = 0; g < 4; ++g)
      esqr[i][g] = *(const f32x4*)(esq_s + w * 64 + i * 32 + 8 * g + 4 * lhi);

  const _Float16* qbase = Af + lhi * 256 + l32 * 8;

  // fold + combine + smin-write for one finished q-tile
  auto finish = [&](const f32x16& a0, const f32x16& a1, int qt) {
    float mv = 3.4e38f; int mi = 0;
#pragma unroll
    for (int g = 0; g < 4; ++g)
#pragma unroll
      for (int r = 0; r < 4; ++r) {
        const int e0 = w * 64 + 8 * g + 4 * lhi + r;          // tile 0
        if (a0[4 * g + r] < mv) { mv = a0[4 * g + r]; mi = e0; }
      }
#pragma unroll
    for (int g = 0; g < 4; ++g)
#pragma unroll
      for (int r = 0; r < 4; ++r) {
        const int e1 = w * 64 + 32 + 8 * g + 4 * lhi + r;     // tile 1 (larger idx)
        if (a1[4 * g + r] < mv) { mv = a1[4 * g + r]; mi = e1; }
      }
    float ov = __shfl_xor(mv, 32, 64);
    int oi = __shfl_xor(mi, 32, 64);
    if (ov < mv || (ov == mv && oi < mi)) { mv = ov; mi = oi; }
    if (lhi == 0) {
      smin[w][qt * 32 + l32] = mv;
      simin[w][qt * 32 + l32] = mi;
    }
  };

  auto mfma24 = [&](const f16x8* qf, f32x16& a0, f32x16& a1) {
#pragma unroll
    for (int g = 0; g < 4; ++g)
#pragma unroll
      for (int r = 0; r < 4; ++r) {
        a0[4 * g + r] = esqr[0][g][r];   // C seed: 0.5||e||^2
        a1[4 * g + r] = esqr[1][g][r];
      }
    __builtin_amdgcn_s_setprio(1);
#pragma unroll
    for (int kb = 0; kb < 4; ++kb) {     // eh . (-ch)
      a0 = __builtin_amdgcn_mfma_f32_32x32x16_f16(ef[0][kb], qf[kb], a0, 0, 0, 0);
      a1 = __builtin_amdgcn_mfma_f32_32x32x16_f16(ef[1][kb], qf[kb], a1, 0, 0, 0);
    }
#pragma unroll
    for (int kb = 0; kb < 4; ++kb) {     // eh . (-cl)
      a0 = __builtin_amdgcn_mfma_f32_32x32x16_f16(ef[0][kb], qf[4 + kb], a0, 0, 0, 0);
      a1 = __builtin_amdgcn_mfma_f32_32x32x16_f16(ef[1][kb], qf[4 + kb], a1, 0, 0, 0);
    }
#pragma unroll
    for (int kb = 0; kb < 4; ++kb) {     // el . (-ch)
      a0 = __builtin_amdgcn_mfma_f32_32x32x16_f16(ef[0][4 + kb], qf[kb], a0, 0, 0, 0);
      a1 = __builtin_amdgcn_mfma_f32_32x32x16_f16(ef[1][4 + kb], qf[kb], a1, 0, 0, 0);
    }
    __builtin_amdgcn_s_setprio(0);
  };

  // ---- main loop: 8 q-tiles, software-pipelined qf double-buffer ----
  f16x8 qfA[8], qfB[8];
#pragma unroll
  for (int kb = 0; kb < 8; ++kb)         // preload qt=0
    qfA[kb] = *(const f16x8*)(qbase + 0 * 4096 + kb * 512);

#pragma unroll
  for (int qt = 0; qt < 8; qt += 2) {
    // prefetch qt+1 BEFORE the qt MFMA burst (DS latency hides under MFMA)
#pragma unroll
    for (int kb = 0; kb < 8; ++kb)
      qfB[kb] = *(const f16x8*)(qbase + (qt + 1) * 4096 + kb * 512);

    f32x16 a0, a1;
    mfma24(qfA, a0, a1);

    if (qt + 2 < 8) {                    // prefetch qt+2 before qt+1's burst
#pragma unroll
      for (int kb = 0; kb < 8; ++kb)
        qfA[kb] = *(const f16x8*)(qbase + (qt + 2) * 4096 + kb * 512);
    }
    finish(a0, a1, qt);                  // fold overlaps qt+1's MFMA issue window

    f32x16 b0, b1;
    mfma24(qfB, b0, b1);
    finish(b0, b1, qt + 1);
  }
  __syncthreads();                       // barrier #2: all smin written

  // ---- combine 8 waves (disjoint ascending entry ranges; tie -> lower index) ----
  if (t < 256) {
    float bv = smin[0][t]; int bi = simin[0][t];
#pragma unroll
    for (int ww = 1; ww < 8; ++ww) {
      float v = smin[ww][t]; int ii = simin[ww][t];
      if (v < bv || (v == bv && ii < bi)) { bv = v; bi = ii; }
    }
    best[t] = bi;
  }
  __syncthreads();

  // ---- gather: exact fp32 rows (L2-hot codebook), coalesced NT stores ----
#pragma unroll
  for (int i2 = 0; i2 < 8; ++i2) {
    const int f = t + 512 * i2;          // 4096 f32x4 per block
    const int q = f >> 4, g = f & 15;
    const int e = best[q];
    f32x4 v = *(const f32x4*)(codebook + e * D_ + g * 4);
    __builtin_nontemporal_store(v, (f32x4*)(out + (qb + q) * D_ + g * 4));
  }
}

extern "C" void kernel_launch(void* const* d_in, const int* in_sizes, int n_in,
                              void* d_out, int out_size, void* d_ws, size_t ws_size,
                              hipStream_t stream) {
  const float* codes = (const float*)d_in[0];
  const float* codebook = (const float*)d_in[1];
  float* out = (float*)d_out;
  const int Q = in_sizes[0] / D_;        // 65536
  const int grid = Q / 256;              // 256
  vq_fused<<<grid, 512, 0, stream>>>(codes, codebook, out);
}